// Round 9
// baseline (502.457 us; speedup 1.0000x reference)
//
#include <hip/hip_runtime.h>
#include <hip/hip_bf16.h>

// GraphConv x2:
//   h   = relu( seg_sum(x[src]->dst) @ Wr1^T + b1 + x @ Wo1^T )
//   out =       seg_sum(h[src]->dst) @ Wr2^T + b2 + h @ Wo2^T
// seg_sum(h[src]) @ W^T == seg_sum((h @ W^T)[src]) -> transform first, aggregate after.
// CSR built in-kernel (partitioned hist + 3-kernel scan + partitioned fill).
// R2: parallel scan. R4: dst-range-partitioned fill. R6: bf16 q1/p2; partitioned hist.
// R7: gemm launch_bounds(256,2) (spill fix); agg uint2 loads; bf16 agg outputs.
// R9: fill -> persistent 2048-block grid (8 blocks/CU co-resident from t=0) so the
//     blockIdx%8->XCD round-robin mapping HOLDS for the whole kernel. R8 showed the
//     12504-block version drifts (WRITE still 73MB, RFO FETCH 50MB): later blocks land
//     on arbitrary XCDs -> csr lines written from multiple XCDs -> line migration.

#define BM 128
#define BK 32
#define NPASS 8
#define FILL_GRID 2048  // 8 blocks/CU * 256 CUs: fully co-resident persistent grid

typedef unsigned short ushort_t;

__device__ __forceinline__ ushort_t f2bf(float f) {
    unsigned int u = __float_as_uint(f);
    unsigned int r = (u + 0x7fff + ((u >> 16) & 1)) >> 16;  // RTNE
    return (ushort_t)r;
}

__device__ __forceinline__ float bf2f(ushort_t v) {
    return __uint_as_float(((unsigned int)v) << 16);
}

__device__ __forceinline__ void bf2x(unsigned int v, float& lo, float& hi) {
    lo = __uint_as_float(v << 16);          // element at lower address
    hi = __uint_as_float(v & 0xffff0000u);  // element at higher address
}

// ---------------- CSR build ----------------

// dst-range-partitioned histogram (unchanged in R9: acts as control vs fill's
// persistent-grid change).
__global__ __launch_bounds__(256) void hist_kernel(const int* __restrict__ dst,
                                                   int* __restrict__ deg, int E, int N) {
    const int pass = blockIdx.x & (NPASS - 1);
    const int chunk = blockIdx.x >> 3;
    const int rangeSize = (N + NPASS - 1) / NPASS;
    const int lo = pass * rangeSize;
    const int hi = (lo + rangeSize < N) ? lo + rangeSize : N;
    const int base = chunk * 1024 + threadIdx.x * 4;
    if (base + 3 < E) {
        const int4 d4 = *(const int4*)(dst + base);
        if (d4.x >= lo && d4.x < hi) atomicAdd(&deg[d4.x], 1);
        if (d4.y >= lo && d4.y < hi) atomicAdd(&deg[d4.y], 1);
        if (d4.z >= lo && d4.z < hi) atomicAdd(&deg[d4.z], 1);
        if (d4.w >= lo && d4.w < hi) atomicAdd(&deg[d4.w], 1);
    } else {
        for (int i = 0; i < 4; ++i) {
            int e = base + i;
            if (e < E) {
                int d = dst[e];
                if (d >= lo && d < hi) atomicAdd(&deg[d], 1);
            }
        }
    }
}

// phase 1: per-block (1024-elem chunk) degree sums
__global__ __launch_bounds__(256) void scan1_kernel(const int* __restrict__ deg,
                                                    int* __restrict__ bsum, int N) {
    int t = threadIdx.x;
    int base = blockIdx.x * 1024 + t * 4;
    int s = 0;
    if (base + 3 < N) {
        int4 v = *(const int4*)(deg + base);
        s = v.x + v.y + v.z + v.w;
    } else {
#pragma unroll
        for (int i = 0; i < 4; ++i)
            if (base + i < N) s += deg[base + i];
    }
#pragma unroll
    for (int d = 32; d > 0; d >>= 1) s += __shfl_down(s, d);
    __shared__ int wsum[4];
    int lane = t & 63, w = t >> 6;
    if (lane == 0) wsum[w] = s;
    __syncthreads();
    if (t == 0) bsum[blockIdx.x] = wsum[0] + wsum[1] + wsum[2] + wsum[3];
}

// phase 2: scan block sums (B <= 256), write exclusive block offsets + off[N]
__global__ __launch_bounds__(256) void scan2_kernel(const int* __restrict__ bsum,
                                                    int* __restrict__ boff,
                                                    int* __restrict__ offN, int B) {
    __shared__ int s[256];
    int t = threadIdx.x;
    int v = (t < B) ? bsum[t] : 0;
    s[t] = v;
    __syncthreads();
    for (int d = 1; d < 256; d <<= 1) {
        int u = (t >= d) ? s[t - d] : 0;
        __syncthreads();
        s[t] += u;
        __syncthreads();
    }
    if (t < B) boff[t] = s[t] - v;   // exclusive
    if (t == B - 1) *offN = s[t];    // total
}

// phase 3: per-block local exclusive scan + block offset -> off, cursor
__global__ __launch_bounds__(256) void scan3_kernel(const int* __restrict__ deg,
                                                    const int* __restrict__ boff,
                                                    int* __restrict__ off,
                                                    int* __restrict__ cursor, int N) {
    int t = threadIdx.x;
    int base = blockIdx.x * 1024 + t * 4;
    int d0 = 0, d1 = 0, d2 = 0, d3 = 0;
    if (base + 3 < N) {
        int4 v = *(const int4*)(deg + base);
        d0 = v.x; d1 = v.y; d2 = v.z; d3 = v.w;
    } else {
        if (base + 0 < N) d0 = deg[base + 0];
        if (base + 1 < N) d1 = deg[base + 1];
        if (base + 2 < N) d2 = deg[base + 2];
    }
    int s = d0 + d1 + d2 + d3;
    int lane = t & 63, w = t >> 6;
    int incl = s;
#pragma unroll
    for (int d = 1; d < 64; d <<= 1) {
        int u = __shfl_up(incl, d);
        if (lane >= d) incl += u;
    }
    __shared__ int wsum[4];
    if (lane == 63) wsum[w] = incl;
    __syncthreads();
    int wpre = 0;
#pragma unroll
    for (int i = 0; i < 3; ++i)
        if (i < w) wpre += wsum[i];
    int excl = incl - s + wpre + boff[blockIdx.x];
    int e0 = excl, e1 = e0 + d0, e2 = e1 + d1, e3 = e2 + d2;
    if (base + 3 < N) {
        *(int4*)(off + base) = make_int4(e0, e1, e2, e3);
        *(int4*)(cursor + base) = make_int4(e0, e1, e2, e3);
    } else {
        if (base + 0 < N) { off[base + 0] = e0; cursor[base + 0] = e0; }
        if (base + 1 < N) { off[base + 1] = e1; cursor[base + 1] = e1; }
        if (base + 2 < N) { off[base + 2] = e2; cursor[base + 2] = e2; }
    }
}

// R9: persistent dst-range-partitioned fill. 2048 blocks co-resident from launch:
// blockIdx%8 -> XCD round-robin mapping holds for the kernel lifetime, so all
// writers of a csr line live on one XCD; its L2 accumulates full lines before a
// single write-back (and no cross-XCD RFO fetches).
__global__ __launch_bounds__(256) void fill_kernel(const int* __restrict__ src,
                                                   const int* __restrict__ dst,
                                                   int* __restrict__ cursor,
                                                   int* __restrict__ csr, int E, int N) {
    const int pass = blockIdx.x & (NPASS - 1);
    const int rangeSize = (N + NPASS - 1) / NPASS;
    const int lo = pass * rangeSize;
    const int hi = (lo + rangeSize < N) ? lo + rangeSize : N;
    const int nChunk = (E + 1023) >> 10;
    for (int chunk = blockIdx.x >> 3; chunk < nChunk; chunk += FILL_GRID / NPASS) {
        const int base = chunk * 1024 + threadIdx.x * 4;
        if (base + 3 < E) {
            const int4 s4 = *(const int4*)(src + base);
            const int4 d4 = *(const int4*)(dst + base);
            if (d4.x >= lo && d4.x < hi) csr[atomicAdd(&cursor[d4.x], 1)] = s4.x;
            if (d4.y >= lo && d4.y < hi) csr[atomicAdd(&cursor[d4.y], 1)] = s4.y;
            if (d4.z >= lo && d4.z < hi) csr[atomicAdd(&cursor[d4.z], 1)] = s4.z;
            if (d4.w >= lo && d4.w < hi) csr[atomicAdd(&cursor[d4.w], 1)] = s4.w;
        } else {
            for (int i = 0; i < 4; ++i) {
                int e = base + i;
                if (e < E) {
                    int d = dst[e];
                    if (d >= lo && d < hi) csr[atomicAdd(&cursor[d], 1)] = src[e];
                }
            }
        }
    }
}

// ---------------- GEMM: OUT[g][j] = sum_k X[g][k] * W[j][k] (+ epilogue) ----------------
// X: [Nrows][128] fp32. W: [BN][128] fp32. EPI: 0 none, 1 relu(AGG+bias+acc), 2 AGG+bias+acc.
// OB: 1 -> OUT bf16, 0 -> fp32. AB: 1 -> AGG bf16, 0 -> fp32.

template <int BN, int EPI, int OB, int AB>
__global__ __launch_bounds__(256, 2)
void gemm_k(const float* __restrict__ X, const float* __restrict__ W,
            const void* __restrict__ AGGv, const float* __restrict__ bias,
            void* __restrict__ OUTv, int Nrows) {
    __shared__ float xs[BK][BM + 4];   // transposed x chunk: xs[k][row]
    __shared__ float wsh[BK][BN + 4];  // transposed W chunk: wsh[k][col]

    const int tid = threadIdx.x;
    const int tc = tid & 15;   // col group
    const int tr = tid >> 4;   // row group (0..15)
    const int rowBase = blockIdx.x * BM;
    constexpr int CG = BN / 64;  // 2 for BN=128, 1 for BN=64

    float acc[8][4 * CG];
#pragma unroll
    for (int i = 0; i < 8; ++i)
#pragma unroll
        for (int j = 0; j < 4 * CG; ++j) acc[i][j] = 0.f;

    const int srow = tid >> 3;       // 0..31
    const int skq = (tid & 7) * 4;   // k offset within chunk: 0,4,..,28

    for (int kc = 0; kc < 128; kc += BK) {
#pragma unroll
        for (int i = 0; i < 4; ++i) {
            int r = srow + i * 32;
            int g = rowBase + r;
            g = g < Nrows ? g : Nrows - 1;
            const float4 v = *(const float4*)(X + (size_t)g * 128 + kc + skq);
            xs[skq + 0][r] = v.x;
            xs[skq + 1][r] = v.y;
            xs[skq + 2][r] = v.z;
            xs[skq + 3][r] = v.w;
        }
#pragma unroll
        for (int i = 0; i < BN / 32; ++i) {
            int j = srow + i * 32;
            const float4 v = *(const float4*)(W + (size_t)j * 128 + kc + skq);
            wsh[skq + 0][j] = v.x;
            wsh[skq + 1][j] = v.y;
            wsh[skq + 2][j] = v.z;
            wsh[skq + 3][j] = v.w;
        }
        __syncthreads();
#pragma unroll
        for (int k = 0; k < BK; ++k) {
            const float4 xa = *(const float4*)&xs[k][tr * 8];
            const float4 xb = *(const float4*)&xs[k][tr * 8 + 4];
            float xr[8] = {xa.x, xa.y, xa.z, xa.w, xb.x, xb.y, xb.z, xb.w};
            float wv[4 * CG];
            const float4 wa = *(const float4*)&wsh[k][tc * 4];
            wv[0] = wa.x; wv[1] = wa.y; wv[2] = wa.z; wv[3] = wa.w;
            if (CG == 2) {
                const float4 wb = *(const float4*)&wsh[k][64 + tc * 4];
                wv[4] = wb.x; wv[5] = wb.y; wv[6] = wb.z; wv[7] = wb.w;
            }
#pragma unroll
            for (int i = 0; i < 8; ++i)
#pragma unroll
                for (int j = 0; j < 4 * CG; ++j) acc[i][j] += xr[i] * wv[j];
        }
        __syncthreads();
    }

    // epilogue
#pragma unroll
    for (int i = 0; i < 8; ++i) {
        int g = rowBase + tr * 8 + i;
        if (g >= Nrows) continue;
#pragma unroll
        for (int cg = 0; cg < CG; ++cg) {
            int c = cg * 64 + tc * 4;
            float4 r;
            r.x = acc[i][cg * 4 + 0];
            r.y = acc[i][cg * 4 + 1];
            r.z = acc[i][cg * 4 + 2];
            r.w = acc[i][cg * 4 + 3];
            if (EPI != 0) {
                float ax, ay, az, aw;
                if (AB) {
                    const ushort_t* A = (const ushort_t*)AGGv;
                    ushort4 a4 = *(const ushort4*)(A + (size_t)g * BN + c);
                    ax = bf2f(a4.x); ay = bf2f(a4.y); az = bf2f(a4.z); aw = bf2f(a4.w);
                } else {
                    const float4 a = *(const float4*)((const float*)AGGv + (size_t)g * BN + c);
                    ax = a.x; ay = a.y; az = a.z; aw = a.w;
                }
                const float4 bb = *(const float4*)(bias + c);
                r.x += ax + bb.x;
                r.y += ay + bb.y;
                r.z += az + bb.z;
                r.w += aw + bb.w;
                if (EPI == 1) {
                    r.x = r.x > 0.f ? r.x : 0.f;
                    r.y = r.y > 0.f ? r.y : 0.f;
                    r.z = r.z > 0.f ? r.z : 0.f;
                    r.w = r.w > 0.f ? r.w : 0.f;
                }
            }
            if (OB) {
                ushort_t* OUT = (ushort_t*)OUTv;
                ushort4 o;
                o.x = f2bf(r.x); o.y = f2bf(r.y); o.z = f2bf(r.z); o.w = f2bf(r.w);
                *(ushort4*)(OUT + (size_t)g * BN + c) = o;
            } else {
                float* OUT = (float*)OUTv;
                *(float4*)(OUT + (size_t)g * BN + c) = r;
            }
        }
    }
}

// ---------------- CSR gather-aggregate (bf16 in, bf16 out) ----------------
// uint2 (4 bf16) per lane: D=128 -> 32 lanes/node, D=64 -> 16 lanes/node.

template <int D, int OB>
__global__ __launch_bounds__(256)
void agg_k(const ushort_t* __restrict__ F, const int* __restrict__ csr,
           const int* __restrict__ off, void* __restrict__ OUTv, int N) {
    constexpr int LPN = (D == 128) ? 32 : 16;  // lanes per node
    constexpr int NPB = 256 / LPN;             // nodes per block
    int n = blockIdx.x * NPB + (threadIdx.x / LPN);
    if (n >= N) return;
    int lane = threadIdx.x & (LPN - 1);
    int b = off[n], e = off[n + 1];
    const size_t col = (size_t)lane * 4;
    float a0 = 0.f, a1 = 0.f, a2 = 0.f, a3 = 0.f;
    int i = b;
    for (; i + 4 <= e; i += 4) {
        int s0 = csr[i], s1 = csr[i + 1], s2 = csr[i + 2], s3 = csr[i + 3];
        uint2 v0 = *(const uint2*)(F + (size_t)s0 * D + col);
        uint2 v1 = *(const uint2*)(F + (size_t)s1 * D + col);
        uint2 v2 = *(const uint2*)(F + (size_t)s2 * D + col);
        uint2 v3 = *(const uint2*)(F + (size_t)s3 * D + col);
        float l, h;
        bf2x(v0.x, l, h); a0 += l; a1 += h;
        bf2x(v0.y, l, h); a2 += l; a3 += h;
        bf2x(v1.x, l, h); a0 += l; a1 += h;
        bf2x(v1.y, l, h); a2 += l; a3 += h;
        bf2x(v2.x, l, h); a0 += l; a1 += h;
        bf2x(v2.y, l, h); a2 += l; a3 += h;
        bf2x(v3.x, l, h); a0 += l; a1 += h;
        bf2x(v3.y, l, h); a2 += l; a3 += h;
    }
    for (; i < e; ++i) {
        uint2 v = *(const uint2*)(F + (size_t)csr[i] * D + col);
        float l, h;
        bf2x(v.x, l, h); a0 += l; a1 += h;
        bf2x(v.y, l, h); a2 += l; a3 += h;
    }
    if (OB) {
        ushort_t* OUT = (ushort_t*)OUTv;
        ushort4 o;
        o.x = f2bf(a0); o.y = f2bf(a1); o.z = f2bf(a2); o.w = f2bf(a3);
        *(ushort4*)(OUT + (size_t)n * D + col) = o;
    } else {
        float* OUT = (float*)OUTv;
        float4 r; r.x = a0; r.y = a1; r.z = a2; r.w = a3;
        *(float4*)(OUT + (size_t)n * D + col) = r;
    }
}

extern "C" void kernel_launch(void* const* d_in, const int* in_sizes, int n_in,
                              void* d_out, int out_size, void* d_ws, size_t ws_size,
                              hipStream_t stream) {
    const float* x   = (const float*)d_in[0];
    const int*   ei  = (const int*)d_in[1];
    const float* Wr1 = (const float*)d_in[2];
    const float* br1 = (const float*)d_in[3];
    const float* Wo1 = (const float*)d_in[4];
    const float* Wr2 = (const float*)d_in[5];
    const float* br2 = (const float*)d_in[6];
    const float* Wo2 = (const float*)d_in[7];
    float* out = (float*)d_out;

    const int N = in_sizes[0] / 128;  // 100000
    const int E = in_sizes[1] / 2;    // 1600000

    const int* srcv = ei;
    const int* dstv = ei + E;

    // workspace layout (16B-aligned sections)
    float*    h    = (float*)d_ws;                      // N*128 fp32
    ushort_t* qb   = (ushort_t*)(h + (size_t)N * 128);  // N*128 bf16 (reused as p2b N*64)
    ushort_t* a1b  = qb + (size_t)N * 128;              // N*128 bf16
    ushort_t* a2b  = a1b + (size_t)N * 128;             // N*64  bf16
    int*      deg  = (int*)(a2b + (size_t)N * 64);      // N
    int*      off  = deg + N;                           // N+1 (padded to N+8)
    int*      cur  = off + N + 8;                       // N
    int*      csr  = cur + N;                           // E
    int*      bsum = csr + E;                           // <=256
    int*      boff = bsum + 256;                        // <=256

    const int gemmBlocks = (N + BM - 1) / BM;
    const int agg128Blocks = (N + 7) / 8;
    const int agg64Blocks = (N + 15) / 16;
    const int B = (N + 1023) / 1024;  // scan blocks (must be <= 256)
    const int edgePassBlocks = ((E + 1023) / 1024) * NPASS;

    // CSR build
    hipMemsetAsync(deg, 0, (size_t)N * sizeof(int), stream);
    hist_kernel<<<edgePassBlocks, 256, 0, stream>>>(dstv, deg, E, N);
    scan1_kernel<<<B, 256, 0, stream>>>(deg, bsum, N);
    scan2_kernel<<<1, 256, 0, stream>>>(bsum, boff, off + N, B);
    scan3_kernel<<<B, 256, 0, stream>>>(deg, boff, off, cur, N);
    fill_kernel<<<FILL_GRID, 256, 0, stream>>>(srcv, dstv, cur, csr, E, N);

    // layer 1: qb = bf16(x @ Wr1^T) ; a1b = bf16(seg_sum(qb)) ; h = relu(a1b + b1 + x @ Wo1^T)
    gemm_k<128, 0, 1, 0><<<gemmBlocks, 256, 0, stream>>>(x, Wr1, nullptr, nullptr, qb, N);
    agg_k<128, 1><<<agg128Blocks, 256, 0, stream>>>(qb, csr, off, a1b, N);
    gemm_k<128, 1, 0, 1><<<gemmBlocks, 256, 0, stream>>>(x, Wo1, a1b, br1, h, N);

    // layer 2: p2b = bf16(h @ Wr2^T) ; a2b = bf16(seg_sum(p2b)) ; out = a2b + b2 + h @ Wo2^T
    gemm_k<64, 0, 1, 0><<<gemmBlocks, 256, 0, stream>>>(h, Wr2, nullptr, nullptr, qb /*p2b*/, N);
    agg_k<64, 1><<<agg64Blocks, 256, 0, stream>>>(qb /*p2b*/, csr, off, a2b, N);
    gemm_k<64, 2, 0, 1><<<gemmBlocks, 256, 0, stream>>>(h, Wo2, a2b, br2, out, N);
}

// Round 10
// 473.208 us; speedup vs baseline: 1.0618x; 1.0618x over previous
//
#include <hip/hip_runtime.h>
#include <hip/hip_bf16.h>

// GraphConv x2 (transform-then-aggregate):
//   qb|hpre = x @ [Wr1;Wo1]^T  (one MFMA gemm, bf16)
//   a1 = seg_sum(qb[src]->dst) ; h = relu(a1 + b1 + hpre)
//   p2|opre = h @ [Wr2;Wo2]^T  (one MFMA gemm)
//   a2 = seg_sum(p2[src]->dst) ; out = a2 + b2 + opre
// CSR built in-kernel (partitioned hist + 3-kernel scan + partitioned fill).
// R4/R9 history: scatter write-amp traced to streaming edge reads evicting the
// csr working set from L2 (persistent-grid placement fix was refuted by R9).
// R10: (a) non-temporal edge loads in hist/fill (evict-first: stop displacing
//      csr/cursor lines); (b) GEMMs moved to MFMA bf16 (VALU fp32 gemms were
//      ~200us aggregate; 16x16x32 bf16 MFMA, fused [Wrel;Wroot] weights).

#define NPASS 8
#define FILL_GRID 2048

typedef unsigned short ushort_t;
using bfrag = __attribute__((ext_vector_type(8))) short;   // 8 bf16 (4 VGPR)
using f32x4 = __attribute__((ext_vector_type(4))) float;   // acc

__device__ __forceinline__ ushort_t f2bf(float f) {
    unsigned int u = __float_as_uint(f);
    unsigned int r = (u + 0x7fff + ((u >> 16) & 1)) >> 16;  // RTNE
    return (ushort_t)r;
}

__device__ __forceinline__ float bf2f(ushort_t v) {
    return __uint_as_float(((unsigned int)v) << 16);
}

__device__ __forceinline__ void bf2x(unsigned int v, float& lo, float& hi) {
    lo = __uint_as_float(v << 16);
    hi = __uint_as_float(v & 0xffff0000u);
}

// non-temporal int4 load (2x 8B nt loads): evict-first in L2, keeps the
// scatter working set (csr/cursor) resident.
__device__ __forceinline__ int4 ldnt_int4(const int* p) {
    unsigned long long a = __builtin_nontemporal_load((const unsigned long long*)p);
    unsigned long long b = __builtin_nontemporal_load(((const unsigned long long*)p) + 1);
    int4 r;
    r.x = (int)(unsigned int)(a & 0xffffffffull);
    r.y = (int)(unsigned int)(a >> 32);
    r.z = (int)(unsigned int)(b & 0xffffffffull);
    r.w = (int)(unsigned int)(b >> 32);
    return r;
}

// ---------------- CSR build ----------------

__global__ __launch_bounds__(256) void hist_kernel(const int* __restrict__ dst,
                                                   int* __restrict__ deg, int E, int N) {
    const int pass = blockIdx.x & (NPASS - 1);
    const int chunk = blockIdx.x >> 3;
    const int rangeSize = (N + NPASS - 1) / NPASS;
    const int lo = pass * rangeSize;
    const int hi = (lo + rangeSize < N) ? lo + rangeSize : N;
    const int base = chunk * 1024 + threadIdx.x * 4;
    if (base + 3 < E) {
        const int4 d4 = ldnt_int4(dst + base);
        if (d4.x >= lo && d4.x < hi) atomicAdd(&deg[d4.x], 1);
        if (d4.y >= lo && d4.y < hi) atomicAdd(&deg[d4.y], 1);
        if (d4.z >= lo && d4.z < hi) atomicAdd(&deg[d4.z], 1);
        if (d4.w >= lo && d4.w < hi) atomicAdd(&deg[d4.w], 1);
    } else {
        for (int i = 0; i < 4; ++i) {
            int e = base + i;
            if (e < E) {
                int d = dst[e];
                if (d >= lo && d < hi) atomicAdd(&deg[d], 1);
            }
        }
    }
}

__global__ __launch_bounds__(256) void scan1_kernel(const int* __restrict__ deg,
                                                    int* __restrict__ bsum, int N) {
    int t = threadIdx.x;
    int base = blockIdx.x * 1024 + t * 4;
    int s = 0;
    if (base + 3 < N) {
        int4 v = *(const int4*)(deg + base);
        s = v.x + v.y + v.z + v.w;
    } else {
#pragma unroll
        for (int i = 0; i < 4; ++i)
            if (base + i < N) s += deg[base + i];
    }
#pragma unroll
    for (int d = 32; d > 0; d >>= 1) s += __shfl_down(s, d);
    __shared__ int wsum[4];
    int lane = t & 63, w = t >> 6;
    if (lane == 0) wsum[w] = s;
    __syncthreads();
    if (t == 0) bsum[blockIdx.x] = wsum[0] + wsum[1] + wsum[2] + wsum[3];
}

__global__ __launch_bounds__(256) void scan2_kernel(const int* __restrict__ bsum,
                                                    int* __restrict__ boff,
                                                    int* __restrict__ offN, int B) {
    __shared__ int s[256];
    int t = threadIdx.x;
    int v = (t < B) ? bsum[t] : 0;
    s[t] = v;
    __syncthreads();
    for (int d = 1; d < 256; d <<= 1) {
        int u = (t >= d) ? s[t - d] : 0;
        __syncthreads();
        s[t] += u;
        __syncthreads();
    }
    if (t < B) boff[t] = s[t] - v;
    if (t == B - 1) *offN = s[t];
}

__global__ __launch_bounds__(256) void scan3_kernel(const int* __restrict__ deg,
                                                    const int* __restrict__ boff,
                                                    int* __restrict__ off,
                                                    int* __restrict__ cursor, int N) {
    int t = threadIdx.x;
    int base = blockIdx.x * 1024 + t * 4;
    int d0 = 0, d1 = 0, d2 = 0, d3 = 0;
    if (base + 3 < N) {
        int4 v = *(const int4*)(deg + base);
        d0 = v.x; d1 = v.y; d2 = v.z; d3 = v.w;
    } else {
        if (base + 0 < N) d0 = deg[base + 0];
        if (base + 1 < N) d1 = deg[base + 1];
        if (base + 2 < N) d2 = deg[base + 2];
    }
    int s = d0 + d1 + d2 + d3;
    int lane = t & 63, w = t >> 6;
    int incl = s;
#pragma unroll
    for (int d = 1; d < 64; d <<= 1) {
        int u = __shfl_up(incl, d);
        if (lane >= d) incl += u;
    }
    __shared__ int wsum[4];
    if (lane == 63) wsum[w] = incl;
    __syncthreads();
    int wpre = 0;
#pragma unroll
    for (int i = 0; i < 3; ++i)
        if (i < w) wpre += wsum[i];
    int excl = incl - s + wpre + boff[blockIdx.x];
    int e0 = excl, e1 = e0 + d0, e2 = e1 + d1, e3 = e2 + d2;
    if (base + 3 < N) {
        *(int4*)(off + base) = make_int4(e0, e1, e2, e3);
        *(int4*)(cursor + base) = make_int4(e0, e1, e2, e3);
    } else {
        if (base + 0 < N) { off[base + 0] = e0; cursor[base + 0] = e0; }
        if (base + 1 < N) { off[base + 1] = e1; cursor[base + 1] = e1; }
        if (base + 2 < N) { off[base + 2] = e2; cursor[base + 2] = e2; }
    }
}

// persistent dst-range-partitioned fill, nt edge loads.
__global__ __launch_bounds__(256) void fill_kernel(const int* __restrict__ src,
                                                   const int* __restrict__ dst,
                                                   int* __restrict__ cursor,
                                                   int* __restrict__ csr, int E, int N) {
    const int pass = blockIdx.x & (NPASS - 1);
    const int rangeSize = (N + NPASS - 1) / NPASS;
    const int lo = pass * rangeSize;
    const int hi = (lo + rangeSize < N) ? lo + rangeSize : N;
    const int nChunk = (E + 1023) >> 10;
    for (int chunk = blockIdx.x >> 3; chunk < nChunk; chunk += FILL_GRID / NPASS) {
        const int base = chunk * 1024 + threadIdx.x * 4;
        if (base + 3 < E) {
            const int4 s4 = ldnt_int4(src + base);
            const int4 d4 = ldnt_int4(dst + base);
            if (d4.x >= lo && d4.x < hi) csr[atomicAdd(&cursor[d4.x], 1)] = s4.x;
            if (d4.y >= lo && d4.y < hi) csr[atomicAdd(&cursor[d4.y], 1)] = s4.y;
            if (d4.z >= lo && d4.z < hi) csr[atomicAdd(&cursor[d4.z], 1)] = s4.z;
            if (d4.w >= lo && d4.w < hi) csr[atomicAdd(&cursor[d4.w], 1)] = s4.w;
        } else {
            for (int i = 0; i < 4; ++i) {
                int e = base + i;
                if (e < E) {
                    int d = dst[e];
                    if (d >= lo && d < hi) csr[atomicAdd(&cursor[d], 1)] = src[e];
                }
            }
        }
    }
}

// ---------------- bf16 conversion ----------------

__global__ __launch_bounds__(256) void cvt_kernel(const float* __restrict__ in,
                                                  ushort_t* __restrict__ out, int n) {
    int base = (blockIdx.x * 256 + threadIdx.x) * 4;
    if (base + 3 < n) {
        float4 v = *(const float4*)(in + base);
        ushort4 o;
        o.x = f2bf(v.x); o.y = f2bf(v.y); o.z = f2bf(v.z); o.w = f2bf(v.w);
        *(ushort4*)(out + base) = o;
    } else {
        for (int i = 0; i < 4 && base + i < n; ++i) out[base + i] = f2bf(in[base + i]);
    }
}

// convert all 4 weight mats into concatenated bf16 buffers:
// wcat1 = [Wr1(128x128); Wo1(128x128)], wcat2 = [Wr2(64x128); Wo2(64x128)]
__global__ __launch_bounds__(256) void cvt_w_kernel(const float* __restrict__ Wr1,
                                                    const float* __restrict__ Wo1,
                                                    const float* __restrict__ Wr2,
                                                    const float* __restrict__ Wo2,
                                                    ushort_t* __restrict__ wcat1,
                                                    ushort_t* __restrict__ wcat2) {
    int i = blockIdx.x * 256 + threadIdx.x;  // elem index
    if (i < 16384) wcat1[i] = f2bf(Wr1[i]);
    else if (i < 32768) wcat1[i] = f2bf(Wo1[i - 16384]);
    else if (i < 40960) wcat2[i - 32768] = f2bf(Wr2[i - 32768]);
    else if (i < 49152) wcat2[i - 32768] = f2bf(Wo2[i - 40960]);
}

// ---------------- MFMA GEMM: D = A(bf16, Nrows x 128) @ Wc(bf16, BN x 128)^T --------
// 16x16x32 bf16 MFMA. A-frag: lane holds A[m0+(l&15)][kk*32+(l>>4)*8 ..+8].
// B-frag: lane holds Wc[n0+(l&15)][same k] (B^T-input form). D: col=l&15,
// row=(l>>4)*4+r  [layouts per cdna_hip_programming.md §3, HW-verified].
// Output split: cols [0,SPLIT) -> O1 (bf16, stride SPLIT);
//               cols [SPLIT,BN) -> O2 (stride BN-SPLIT; fp32 if O2F else bf16).

template <int BN, int SPLIT, int O2F>
__global__ __launch_bounds__(256, 2)
void mfma_gemm(const ushort_t* __restrict__ A, const ushort_t* __restrict__ Wc,
               ushort_t* __restrict__ O1, void* __restrict__ O2v, int Nrows) {
    constexpr int NT = BN / 16;  // N-tiles per wave (wave covers full BN width)
    const int w = threadIdx.x >> 6;
    const int lane = threadIdx.x & 63;
    const int m0 = blockIdx.x * 64 + w * 16;
    const int lm = lane & 15;
    const int lk8 = (lane >> 4) * 8;

    f32x4 acc[NT];
#pragma unroll
    for (int t = 0; t < NT; ++t) {
        acc[t][0] = 0.f; acc[t][1] = 0.f; acc[t][2] = 0.f; acc[t][3] = 0.f;
    }

    int ar = m0 + lm;
    ar = ar < Nrows ? ar : Nrows - 1;  // clamp tail (writes are guarded)
    const ushort_t* Arow = A + (size_t)ar * 128;

#pragma unroll
    for (int kk = 0; kk < 4; ++kk) {
        const bfrag af = *(const bfrag*)(Arow + kk * 32 + lk8);
#pragma unroll
        for (int t = 0; t < NT; ++t) {
            const bfrag bf = *(const bfrag*)(Wc + ((size_t)(t * 16 + lm) << 7) + kk * 32 + lk8);
            acc[t] = __builtin_amdgcn_mfma_f32_16x16x32_bf16(af, bf, acc[t], 0, 0, 0);
        }
    }

    const int rbase = m0 + (lane >> 4) * 4;
#pragma unroll
    for (int t = 0; t < NT; ++t) {
        const int col = t * 16 + lm;
#pragma unroll
        for (int r = 0; r < 4; ++r) {
            const int row = rbase + r;
            if (row >= Nrows) continue;
            const float v = acc[t][r];
            if (col < SPLIT) {
                O1[(size_t)row * SPLIT + col] = f2bf(v);
            } else {
                if (O2F) ((float*)O2v)[(size_t)row * (BN - SPLIT) + (col - SPLIT)] = v;
                else ((ushort_t*)O2v)[(size_t)row * (BN - SPLIT) + (col - SPLIT)] = f2bf(v);
            }
        }
    }
}

// ---------------- CSR gather-aggregate (bf16 in, bf16 out) ----------------

template <int D, int OB>
__global__ __launch_bounds__(256)
void agg_k(const ushort_t* __restrict__ F, const int* __restrict__ csr,
           const int* __restrict__ off, void* __restrict__ OUTv, int N) {
    constexpr int LPN = (D == 128) ? 32 : 16;
    constexpr int NPB = 256 / LPN;
    int n = blockIdx.x * NPB + (threadIdx.x / LPN);
    if (n >= N) return;
    int lane = threadIdx.x & (LPN - 1);
    int b = off[n], e = off[n + 1];
    const size_t col = (size_t)lane * 4;
    float a0 = 0.f, a1 = 0.f, a2 = 0.f, a3 = 0.f;
    int i = b;
    for (; i + 4 <= e; i += 4) {
        int s0 = csr[i], s1 = csr[i + 1], s2 = csr[i + 2], s3 = csr[i + 3];
        uint2 v0 = *(const uint2*)(F + (size_t)s0 * D + col);
        uint2 v1 = *(const uint2*)(F + (size_t)s1 * D + col);
        uint2 v2 = *(const uint2*)(F + (size_t)s2 * D + col);
        uint2 v3 = *(const uint2*)(F + (size_t)s3 * D + col);
        float l, h;
        bf2x(v0.x, l, h); a0 += l; a1 += h;
        bf2x(v0.y, l, h); a2 += l; a3 += h;
        bf2x(v1.x, l, h); a0 += l; a1 += h;
        bf2x(v1.y, l, h); a2 += l; a3 += h;
        bf2x(v2.x, l, h); a0 += l; a1 += h;
        bf2x(v2.y, l, h); a2 += l; a3 += h;
        bf2x(v3.x, l, h); a0 += l; a1 += h;
        bf2x(v3.y, l, h); a2 += l; a3 += h;
    }
    for (; i < e; ++i) {
        uint2 v = *(const uint2*)(F + (size_t)csr[i] * D + col);
        float l, h;
        bf2x(v.x, l, h); a0 += l; a1 += h;
        bf2x(v.y, l, h); a2 += l; a3 += h;
    }
    if (OB) {
        ushort_t* OUT = (ushort_t*)OUTv;
        ushort4 o;
        o.x = f2bf(a0); o.y = f2bf(a1); o.z = f2bf(a2); o.w = f2bf(a3);
        *(ushort4*)(OUT + (size_t)n * D + col) = o;
    } else {
        float* OUT = (float*)OUTv;
        float4 r; r.x = a0; r.y = a1; r.z = a2; r.w = a3;
        *(float4*)(OUT + (size_t)n * D + col) = r;
    }
}

// ---------------- epilogues ----------------

// h = relu(a1 + b1 + hpre)  [all N*128; a1,hpre,h bf16; b1 fp32]
__global__ __launch_bounds__(256) void epi1_kernel(const ushort_t* __restrict__ a1,
                                                   const ushort_t* __restrict__ hpre,
                                                   const float* __restrict__ b1,
                                                   ushort_t* __restrict__ h, int total) {
    int base = (blockIdx.x * 256 + threadIdx.x) * 8;
    if (base + 7 >= total) {
        for (int i = 0; i < 8 && base + i < total; ++i) {
            float v = bf2f(a1[base + i]) + b1[(base + i) & 127] + bf2f(hpre[base + i]);
            h[base + i] = f2bf(v > 0.f ? v : 0.f);
        }
        return;
    }
    uint4 av = *(const uint4*)(a1 + base);
    uint4 pv = *(const uint4*)(hpre + base);
    int c0 = base & 127;
    float4 bA = *(const float4*)(b1 + c0);
    float4 bB = *(const float4*)(b1 + c0 + 4);
    float bb[8] = {bA.x, bA.y, bA.z, bA.w, bB.x, bB.y, bB.z, bB.w};
    unsigned int aw[4] = {av.x, av.y, av.z, av.w};
    unsigned int pw[4] = {pv.x, pv.y, pv.z, pv.w};
    ushort4 o[2];
    ushort_t res[8];
#pragma unroll
    for (int q = 0; q < 4; ++q) {
        float al, ah, pl, ph;
        bf2x(aw[q], al, ah);
        bf2x(pw[q], pl, ph);
        float v0 = al + bb[q * 2 + 0] + pl;
        float v1 = ah + bb[q * 2 + 1] + ph;
        res[q * 2 + 0] = f2bf(v0 > 0.f ? v0 : 0.f);
        res[q * 2 + 1] = f2bf(v1 > 0.f ? v1 : 0.f);
    }
    o[0].x = res[0]; o[0].y = res[1]; o[0].z = res[2]; o[0].w = res[3];
    o[1].x = res[4]; o[1].y = res[5]; o[1].z = res[6]; o[1].w = res[7];
    *(ushort4*)(h + base) = o[0];
    *(ushort4*)(h + base + 4) = o[1];
}

// out = a2 + b2 + opre  [N*64; a2 bf16, opre fp32, out fp32]
__global__ __launch_bounds__(256) void epi2_kernel(const ushort_t* __restrict__ a2,
                                                   const float* __restrict__ opre,
                                                   const float* __restrict__ b2,
                                                   float* __restrict__ out, int total) {
    int base = (blockIdx.x * 256 + threadIdx.x) * 4;
    if (base + 3 >= total) {
        for (int i = 0; i < 4 && base + i < total; ++i)
            out[base + i] = bf2f(a2[base + i]) + b2[(base + i) & 63] + opre[base + i];
        return;
    }
    uint2 av = *(const uint2*)(a2 + base);
    float4 ov = *(const float4*)(opre + base);
    float4 bv = *(const float4*)(b2 + (base & 63));
    float al, ah, bl, bh;
    bf2x(av.x, al, ah);
    bf2x(av.y, bl, bh);
    float4 r;
    r.x = al + bv.x + ov.x;
    r.y = ah + bv.y + ov.y;
    r.z = bl + bv.z + ov.z;
    r.w = bh + bv.w + ov.w;
    *(float4*)(out + base) = r;
}

extern "C" void kernel_launch(void* const* d_in, const int* in_sizes, int n_in,
                              void* d_out, int out_size, void* d_ws, size_t ws_size,
                              hipStream_t stream) {
    const float* x   = (const float*)d_in[0];
    const int*   ei  = (const int*)d_in[1];
    const float* Wr1 = (const float*)d_in[2];
    const float* br1 = (const float*)d_in[3];
    const float* Wo1 = (const float*)d_in[4];
    const float* Wr2 = (const float*)d_in[5];
    const float* br2 = (const float*)d_in[6];
    const float* Wo2 = (const float*)d_in[7];
    float* out = (float*)d_out;

    const int N = in_sizes[0] / 128;  // 100000
    const int E = in_sizes[1] / 2;    // 1600000

    const int* srcv = ei;
    const int* dstv = ei + E;

    // workspace (buffers reused across phases; all 16B-aligned):
    // BUF_A: xb then h (N*128 bf16). BUF_B: qb then p2b (N*128 bf16).
    // BUF_C: hpre (N*128 bf16) then opre (N*64 fp32)  [same byte size].
    // BUF_D: a1b (N*128 bf16) then a2b (N*64 bf16).
    ushort_t* bufA = (ushort_t*)d_ws;                    // N*128 bf16
    ushort_t* bufB = bufA + (size_t)N * 128;             // N*128 bf16
    ushort_t* bufC = bufB + (size_t)N * 128;             // N*128 bf16 / N*64 fp32
    ushort_t* bufD = bufC + (size_t)N * 128;             // N*128 bf16
    ushort_t* wcat1 = bufD + (size_t)N * 128;            // 256*128 bf16
    ushort_t* wcat2 = wcat1 + 256 * 128;                 // 128*128 bf16
    int*      deg  = (int*)(wcat2 + 128 * 128);          // N
    int*      off  = deg + N;                            // N+1 (pad 8)
    int*      cur  = off + N + 8;                        // N
    int*      csr  = cur + N;                            // E
    int*      bsum = csr + E;                            // <=256
    int*      boff = bsum + 256;                         // <=256

    const int B = (N + 1023) / 1024;
    const int edgePassBlocks = ((E + 1023) / 1024) * NPASS;
    const int gemmBlocks = (N + 63) / 64;
    const int agg128Blocks = (N + 7) / 8;
    const int agg64Blocks = (N + 15) / 16;
    const int cvtXBlocks = (N * 128 / 4 + 255) / 256;
    const int epi1Blocks = (N * 128 / 8 + 255) / 256;
    const int epi2Blocks = (N * 64 / 4 + 255) / 256;

    // CSR build
    hipMemsetAsync(deg, 0, (size_t)N * sizeof(int), stream);
    hist_kernel<<<edgePassBlocks, 256, 0, stream>>>(dstv, deg, E, N);
    scan1_kernel<<<B, 256, 0, stream>>>(deg, bsum, N);
    scan2_kernel<<<1, 256, 0, stream>>>(bsum, boff, off + N, B);
    scan3_kernel<<<B, 256, 0, stream>>>(deg, boff, off, cur, N);
    fill_kernel<<<FILL_GRID, 256, 0, stream>>>(srcv, dstv, cur, csr, E, N);

    // bf16 conversions
    cvt_kernel<<<cvtXBlocks, 256, 0, stream>>>(x, bufA /*xb*/, N * 128);
    cvt_w_kernel<<<192, 256, 0, stream>>>(Wr1, Wo1, Wr2, Wo2, wcat1, wcat2);

    // layer 1: [qb | hpre] = xb @ wcat1^T ; a1b = seg_sum(qb) ; h = relu(a1b+b1+hpre)
    mfma_gemm<256, 128, 0><<<gemmBlocks, 256, 0, stream>>>(bufA, wcat1, bufB /*qb*/,
                                                           bufC /*hpre*/, N);
    agg_k<128, 1><<<agg128Blocks, 256, 0, stream>>>(bufB, csr, off, bufD /*a1b*/, N);
    epi1_kernel<<<epi1Blocks, 256, 0, stream>>>(bufD, bufC, br1, bufA /*h*/, N * 128);

    // layer 2: [p2b | opre] = h @ wcat2^T ; a2b = seg_sum(p2b) ; out = a2b+b2+opre
    mfma_gemm<128, 64, 1><<<gemmBlocks, 256, 0, stream>>>(bufA, wcat2, bufB /*p2b*/,
                                                          bufC /*opre fp32*/, N);
    agg_k<64, 1><<<agg64Blocks, 256, 0, stream>>>(bufB, csr, off, bufD /*a2b*/, N);
    epi2_kernel<<<epi2Blocks, 256, 0, stream>>>(bufD, (const float*)bufC, br2, out, N * 64);
}

// Round 11
// 456.064 us; speedup vs baseline: 1.1017x; 1.0376x over previous
//
#include <hip/hip_runtime.h>
#include <hip/hip_bf16.h>

// GraphConv x2 (transform-then-aggregate, fused epilogues):
//   [qb | hpre] = x @ [Wr1;Wo1]^T           (MFMA bf16, fp32-A in-register cvt)
//   h = relu(seg_sum(qb) + b1 + hpre)       (fused gather+epilogue)
//   [p2 | opre] = h @ [Wr2;Wo2]^T           (MFMA bf16)
//   out = seg_sum(p2) + b2 + opre           (fused gather+epilogue)
// CSR built in-kernel (partitioned hist + 3-kernel scan + partitioned fill).
// R11: (a) fused epi1/epi2 into agg kernels, cvt into gemm (-3 dispatches,
//      -130MB traffic, a1/a2 stay fp32); (b) fill pass mapping flipped to
//      CHUNKED (blockIdx>>8) to discriminate XCD-mapping hypothesis vs
//      atomic-throughput-bound (R9 persistent round-robin + R10 nt-loads both
//      refuted; hist stays round-robin as control).

#define NPASS 8
#define FILL_GRID 2048

typedef unsigned short ushort_t;
using bfrag = __attribute__((ext_vector_type(8))) short;   // 8 bf16 (4 VGPR)
using f32x4 = __attribute__((ext_vector_type(4))) float;   // acc

__device__ __forceinline__ ushort_t f2bf(float f) {
    unsigned int u = __float_as_uint(f);
    unsigned int r = (u + 0x7fff + ((u >> 16) & 1)) >> 16;  // RTNE
    return (ushort_t)r;
}

__device__ __forceinline__ float bf2f(ushort_t v) {
    return __uint_as_float(((unsigned int)v) << 16);
}

__device__ __forceinline__ void bf2x(unsigned int v, float& lo, float& hi) {
    lo = __uint_as_float(v << 16);
    hi = __uint_as_float(v & 0xffff0000u);
}

__device__ __forceinline__ int4 ldnt_int4(const int* p) {
    unsigned long long a = __builtin_nontemporal_load((const unsigned long long*)p);
    unsigned long long b = __builtin_nontemporal_load(((const unsigned long long*)p) + 1);
    int4 r;
    r.x = (int)(unsigned int)(a & 0xffffffffull);
    r.y = (int)(unsigned int)(a >> 32);
    r.z = (int)(unsigned int)(b & 0xffffffffull);
    r.w = (int)(unsigned int)(b >> 32);
    return r;
}

// ---------------- CSR build ----------------

// round-robin partitioned hist (CONTROL for fill's chunked experiment)
__global__ __launch_bounds__(256) void hist_kernel(const int* __restrict__ dst,
                                                   int* __restrict__ deg, int E, int N) {
    const int pass = blockIdx.x & (NPASS - 1);
    const int chunk = blockIdx.x >> 3;
    const int rangeSize = (N + NPASS - 1) / NPASS;
    const int lo = pass * rangeSize;
    const int hi = (lo + rangeSize < N) ? lo + rangeSize : N;
    const int base = chunk * 1024 + threadIdx.x * 4;
    if (base + 3 < E) {
        const int4 d4 = ldnt_int4(dst + base);
        if (d4.x >= lo && d4.x < hi) atomicAdd(&deg[d4.x], 1);
        if (d4.y >= lo && d4.y < hi) atomicAdd(&deg[d4.y], 1);
        if (d4.z >= lo && d4.z < hi) atomicAdd(&deg[d4.z], 1);
        if (d4.w >= lo && d4.w < hi) atomicAdd(&deg[d4.w], 1);
    } else {
        for (int i = 0; i < 4; ++i) {
            int e = base + i;
            if (e < E) {
                int d = dst[e];
                if (d >= lo && d < hi) atomicAdd(&deg[d], 1);
            }
        }
    }
}

__global__ __launch_bounds__(256) void scan1_kernel(const int* __restrict__ deg,
                                                    int* __restrict__ bsum, int N) {
    int t = threadIdx.x;
    int base = blockIdx.x * 1024 + t * 4;
    int s = 0;
    if (base + 3 < N) {
        int4 v = *(const int4*)(deg + base);
        s = v.x + v.y + v.z + v.w;
    } else {
#pragma unroll
        for (int i = 0; i < 4; ++i)
            if (base + i < N) s += deg[base + i];
    }
#pragma unroll
    for (int d = 32; d > 0; d >>= 1) s += __shfl_down(s, d);
    __shared__ int wsum[4];
    int lane = t & 63, w = t >> 6;
    if (lane == 0) wsum[w] = s;
    __syncthreads();
    if (t == 0) bsum[blockIdx.x] = wsum[0] + wsum[1] + wsum[2] + wsum[3];
}

__global__ __launch_bounds__(256) void scan2_kernel(const int* __restrict__ bsum,
                                                    int* __restrict__ boff,
                                                    int* __restrict__ offN, int B) {
    __shared__ int s[256];
    int t = threadIdx.x;
    int v = (t < B) ? bsum[t] : 0;
    s[t] = v;
    __syncthreads();
    for (int d = 1; d < 256; d <<= 1) {
        int u = (t >= d) ? s[t - d] : 0;
        __syncthreads();
        s[t] += u;
        __syncthreads();
    }
    if (t < B) boff[t] = s[t] - v;
    if (t == B - 1) *offN = s[t];
}

__global__ __launch_bounds__(256) void scan3_kernel(const int* __restrict__ deg,
                                                    const int* __restrict__ boff,
                                                    int* __restrict__ off,
                                                    int* __restrict__ cursor, int N) {
    int t = threadIdx.x;
    int base = blockIdx.x * 1024 + t * 4;
    int d0 = 0, d1 = 0, d2 = 0, d3 = 0;
    if (base + 3 < N) {
        int4 v = *(const int4*)(deg + base);
        d0 = v.x; d1 = v.y; d2 = v.z; d3 = v.w;
    } else {
        if (base + 0 < N) d0 = deg[base + 0];
        if (base + 1 < N) d1 = deg[base + 1];
        if (base + 2 < N) d2 = deg[base + 2];
    }
    int s = d0 + d1 + d2 + d3;
    int lane = t & 63, w = t >> 6;
    int incl = s;
#pragma unroll
    for (int d = 1; d < 64; d <<= 1) {
        int u = __shfl_up(incl, d);
        if (lane >= d) incl += u;
    }
    __shared__ int wsum[4];
    if (lane == 63) wsum[w] = incl;
    __syncthreads();
    int wpre = 0;
#pragma unroll
    for (int i = 0; i < 3; ++i)
        if (i < w) wpre += wsum[i];
    int excl = incl - s + wpre + boff[blockIdx.x];
    int e0 = excl, e1 = e0 + d0, e2 = e1 + d1, e3 = e2 + d2;
    if (base + 3 < N) {
        *(int4*)(off + base) = make_int4(e0, e1, e2, e3);
        *(int4*)(cursor + base) = make_int4(e0, e1, e2, e3);
    } else {
        if (base + 0 < N) { off[base + 0] = e0; cursor[base + 0] = e0; }
        if (base + 1 < N) { off[base + 1] = e1; cursor[base + 1] = e1; }
        if (base + 2 < N) { off[base + 2] = e2; cursor[base + 2] = e2; }
    }
}

// R11: persistent fill with CHUNKED pass mapping (blocks [pass*256, pass*256+255]
// own dst-range pass). If XCD assignment is chunked, each pass's scatter targets
// stay on one XCD's L2 -> WRITE collapses. If unchanged vs R10 -> fill is
// memory-side-atomic-bound, stop optimizing.
__global__ __launch_bounds__(256) void fill_kernel(const int* __restrict__ src,
                                                   const int* __restrict__ dst,
                                                   int* __restrict__ cursor,
                                                   int* __restrict__ csr, int E, int N) {
    const int pass = blockIdx.x >> 8;            // 256 consecutive blocks per pass
    const int rangeSize = (N + NPASS - 1) / NPASS;
    const int lo = pass * rangeSize;
    const int hi = (lo + rangeSize < N) ? lo + rangeSize : N;
    const int nChunk = (E + 1023) >> 10;
    for (int chunk = (blockIdx.x & 255); chunk < nChunk; chunk += FILL_GRID / NPASS) {
        const int base = chunk * 1024 + threadIdx.x * 4;
        if (base + 3 < E) {
            const int4 s4 = ldnt_int4(src + base);
            const int4 d4 = ldnt_int4(dst + base);
            if (d4.x >= lo && d4.x < hi) csr[atomicAdd(&cursor[d4.x], 1)] = s4.x;
            if (d4.y >= lo && d4.y < hi) csr[atomicAdd(&cursor[d4.y], 1)] = s4.y;
            if (d4.z >= lo && d4.z < hi) csr[atomicAdd(&cursor[d4.z], 1)] = s4.z;
            if (d4.w >= lo && d4.w < hi) csr[atomicAdd(&cursor[d4.w], 1)] = s4.w;
        } else {
            for (int i = 0; i < 4; ++i) {
                int e = base + i;
                if (e < E) {
                    int d = dst[e];
                    if (d >= lo && d < hi) csr[atomicAdd(&cursor[d], 1)] = src[e];
                }
            }
        }
    }
}

// ---------------- weight conversion ----------------
// wcat1 = [Wr1;Wo1] (256x128), wcat2 = [Wr2;Wo2] (128x128), bf16
__global__ __launch_bounds__(256) void cvt_w_kernel(const float* __restrict__ Wr1,
                                                    const float* __restrict__ Wo1,
                                                    const float* __restrict__ Wr2,
                                                    const float* __restrict__ Wo2,
                                                    ushort_t* __restrict__ wcat1,
                                                    ushort_t* __restrict__ wcat2) {
    int i = blockIdx.x * 256 + threadIdx.x;
    if (i < 16384) wcat1[i] = f2bf(Wr1[i]);
    else if (i < 32768) wcat1[i] = f2bf(Wo1[i - 16384]);
    else if (i < 40960) wcat2[i - 32768] = f2bf(Wr2[i - 32768]);
    else if (i < 49152) wcat2[i - 32768] = f2bf(Wo2[i - 40960]);
}

// ---------------- MFMA GEMM: D = A(Nrows x 128) @ Wc(BN x 128)^T --------------
// 16x16x32 bf16 MFMA (layouts HW-verified by R10 pass). AF: 1 -> A fp32 (cvt
// in-register), 0 -> A bf16. Output split: cols [0,SPLIT) -> O1 bf16;
// [SPLIT,BN) -> O2 (fp32 if O2F else bf16).

template <int BN, int SPLIT, int O2F, int AF>
__global__ __launch_bounds__(256, 2)
void mfma_gemm(const void* __restrict__ Av, const ushort_t* __restrict__ Wc,
               ushort_t* __restrict__ O1, void* __restrict__ O2v, int Nrows) {
    constexpr int NT = BN / 16;
    const int w = threadIdx.x >> 6;
    const int lane = threadIdx.x & 63;
    const int m0 = blockIdx.x * 64 + w * 16;
    const int lm = lane & 15;
    const int lk8 = (lane >> 4) * 8;

    f32x4 acc[NT];
#pragma unroll
    for (int t = 0; t < NT; ++t) {
        acc[t][0] = 0.f; acc[t][1] = 0.f; acc[t][2] = 0.f; acc[t][3] = 0.f;
    }

    int ar = m0 + lm;
    ar = ar < Nrows ? ar : Nrows - 1;  // clamp tail (writes guarded)

#pragma unroll
    for (int kk = 0; kk < 4; ++kk) {
        bfrag af;
        if (AF) {
            const float* Arow = ((const float*)Av) + (size_t)ar * 128;
            const float4 fa = *(const float4*)(Arow + kk * 32 + lk8);
            const float4 fb = *(const float4*)(Arow + kk * 32 + lk8 + 4);
            af[0] = (short)f2bf(fa.x); af[1] = (short)f2bf(fa.y);
            af[2] = (short)f2bf(fa.z); af[3] = (short)f2bf(fa.w);
            af[4] = (short)f2bf(fb.x); af[5] = (short)f2bf(fb.y);
            af[6] = (short)f2bf(fb.z); af[7] = (short)f2bf(fb.w);
        } else {
            const ushort_t* Arow = ((const ushort_t*)Av) + (size_t)ar * 128;
            af = *(const bfrag*)(Arow + kk * 32 + lk8);
        }
#pragma unroll
        for (int t = 0; t < NT; ++t) {
            const bfrag bf = *(const bfrag*)(Wc + ((size_t)(t * 16 + lm) << 7) + kk * 32 + lk8);
            acc[t] = __builtin_amdgcn_mfma_f32_16x16x32_bf16(af, bf, acc[t], 0, 0, 0);
        }
    }

    const int rbase = m0 + (lane >> 4) * 4;
#pragma unroll
    for (int t = 0; t < NT; ++t) {
        const int col = t * 16 + lm;
#pragma unroll
        for (int r = 0; r < 4; ++r) {
            const int row = rbase + r;
            if (row >= Nrows) continue;
            const float v = acc[t][r];
            if (col < SPLIT) {
                O1[(size_t)row * SPLIT + col] = f2bf(v);
            } else {
                if (O2F) ((float*)O2v)[(size_t)row * (BN - SPLIT) + (col - SPLIT)] = v;
                else ((ushort_t*)O2v)[(size_t)row * (BN - SPLIT) + (col - SPLIT)] = f2bf(v);
            }
        }
    }
}

// ---------------- fused CSR gather-aggregate + epilogue ----------------
// MODE 1: h = relu(agg + bias + hpre)   [hpre bf16, h bf16, D=128]
// MODE 2: out = agg + bias + opre       [opre fp32, out fp32, D=64]

template <int D, int MODE>
__global__ __launch_bounds__(256)
void agg_k(const ushort_t* __restrict__ F, const int* __restrict__ csr,
           const int* __restrict__ off, const void* __restrict__ PRE,
           const float* __restrict__ bias, void* __restrict__ OUTv, int N) {
    constexpr int LPN = (D == 128) ? 32 : 16;
    constexpr int NPB = 256 / LPN;
    int n = blockIdx.x * NPB + (threadIdx.x / LPN);
    if (n >= N) return;
    int lane = threadIdx.x & (LPN - 1);
    int b = off[n], e = off[n + 1];
    const size_t col = (size_t)lane * 4;
    float a0 = 0.f, a1 = 0.f, a2 = 0.f, a3 = 0.f;
    int i = b;
    for (; i + 4 <= e; i += 4) {
        int s0 = csr[i], s1 = csr[i + 1], s2 = csr[i + 2], s3 = csr[i + 3];
        uint2 v0 = *(const uint2*)(F + (size_t)s0 * D + col);
        uint2 v1 = *(const uint2*)(F + (size_t)s1 * D + col);
        uint2 v2 = *(const uint2*)(F + (size_t)s2 * D + col);
        uint2 v3 = *(const uint2*)(F + (size_t)s3 * D + col);
        float l, h;
        bf2x(v0.x, l, h); a0 += l; a1 += h;
        bf2x(v0.y, l, h); a2 += l; a3 += h;
        bf2x(v1.x, l, h); a0 += l; a1 += h;
        bf2x(v1.y, l, h); a2 += l; a3 += h;
        bf2x(v2.x, l, h); a0 += l; a1 += h;
        bf2x(v2.y, l, h); a2 += l; a3 += h;
        bf2x(v3.x, l, h); a0 += l; a1 += h;
        bf2x(v3.y, l, h); a2 += l; a3 += h;
    }
    for (; i < e; ++i) {
        uint2 v = *(const uint2*)(F + (size_t)csr[i] * D + col);
        float l, h;
        bf2x(v.x, l, h); a0 += l; a1 += h;
        bf2x(v.y, l, h); a2 += l; a3 += h;
    }

    const float4 bv = *(const float4*)(bias + col);
    if (MODE == 1) {
        uint2 pv = *(const uint2*)((const ushort_t*)PRE + (size_t)n * D + col);
        float p0, p1, p2, p3;
        bf2x(pv.x, p0, p1);
        bf2x(pv.y, p2, p3);
        float v0 = a0 + bv.x + p0;
        float v1 = a1 + bv.y + p1;
        float v2 = a2 + bv.z + p2;
        float v3 = a3 + bv.w + p3;
        ushort4 o;
        o.x = f2bf(v0 > 0.f ? v0 : 0.f);
        o.y = f2bf(v1 > 0.f ? v1 : 0.f);
        o.z = f2bf(v2 > 0.f ? v2 : 0.f);
        o.w = f2bf(v3 > 0.f ? v3 : 0.f);
        *(ushort4*)((ushort_t*)OUTv + (size_t)n * D + col) = o;
    } else {
        float4 ov = *(const float4*)((const float*)PRE + (size_t)n * D + col);
        float4 r;
        r.x = a0 + bv.x + ov.x;
        r.y = a1 + bv.y + ov.y;
        r.z = a2 + bv.z + ov.z;
        r.w = a3 + bv.w + ov.w;
        *(float4*)((float*)OUTv + (size_t)n * D + col) = r;
    }
}

extern "C" void kernel_launch(void* const* d_in, const int* in_sizes, int n_in,
                              void* d_out, int out_size, void* d_ws, size_t ws_size,
                              hipStream_t stream) {
    const float* x   = (const float*)d_in[0];
    const int*   ei  = (const int*)d_in[1];
    const float* Wr1 = (const float*)d_in[2];
    const float* br1 = (const float*)d_in[3];
    const float* Wo1 = (const float*)d_in[4];
    const float* Wr2 = (const float*)d_in[5];
    const float* br2 = (const float*)d_in[6];
    const float* Wo2 = (const float*)d_in[7];
    float* out = (float*)d_out;

    const int N = in_sizes[0] / 128;  // 100000
    const int E = in_sizes[1] / 2;    // 1600000

    const int* srcv = ei;
    const int* dstv = ei + E;

    // workspace:
    // bufH: h (N*128 bf16). bufB: qb/p2b (N*128 bf16).
    // bufC: hpre (N*128 bf16) then opre (N*64 fp32) — same byte size.
    ushort_t* bufH = (ushort_t*)d_ws;                    // N*128 bf16
    ushort_t* bufB = bufH + (size_t)N * 128;             // N*128 bf16
    ushort_t* bufC = bufB + (size_t)N * 128;             // N*128 bf16 / N*64 fp32
    ushort_t* wcat1 = bufC + (size_t)N * 128;            // 256*128 bf16
    ushort_t* wcat2 = wcat1 + 256 * 128;                 // 128*128 bf16
    int*      deg  = (int*)(wcat2 + 128 * 128);          // N
    int*      off  = deg + N;                            // N+1 (pad 8)
    int*      cur  = off + N + 8;                        // N
    int*      csr  = cur + N;                            // E
    int*      bsum = csr + E;                            // <=256
    int*      boff = bsum + 256;                         // <=256

    const int B = (N + 1023) / 1024;
    const int edgePassBlocks = ((E + 1023) / 1024) * NPASS;
    const int gemmBlocks = (N + 63) / 64;
    const int agg128Blocks = (N + 7) / 8;
    const int agg64Blocks = (N + 15) / 16;

    // CSR build
    hipMemsetAsync(deg, 0, (size_t)N * sizeof(int), stream);
    hist_kernel<<<edgePassBlocks, 256, 0, stream>>>(dstv, deg, E, N);
    scan1_kernel<<<B, 256, 0, stream>>>(deg, bsum, N);
    scan2_kernel<<<1, 256, 0, stream>>>(bsum, boff, off + N, B);
    scan3_kernel<<<B, 256, 0, stream>>>(deg, boff, off, cur, N);
    fill_kernel<<<FILL_GRID, 256, 0, stream>>>(srcv, dstv, cur, csr, E, N);

    cvt_w_kernel<<<192, 256, 0, stream>>>(Wr1, Wo1, Wr2, Wo2, wcat1, wcat2);

    // layer 1: [qb|hpre] = x @ wcat1^T ; h = relu(seg_sum(qb)+b1+hpre)
    mfma_gemm<256, 128, 0, 1><<<gemmBlocks, 256, 0, stream>>>(x, wcat1, bufB /*qb*/,
                                                              bufC /*hpre*/, N);
    agg_k<128, 1><<<agg128Blocks, 256, 0, stream>>>(bufB, csr, off, bufC, br1,
                                                    bufH /*h*/, N);

    // layer 2: [p2|opre] = h @ wcat2^T ; out = seg_sum(p2)+b2+opre
    mfma_gemm<128, 64, 1, 0><<<gemmBlocks, 256, 0, stream>>>(bufH, wcat2, bufB /*p2b*/,
                                                             bufC /*opre fp32*/, N);
    agg_k<64, 2><<<agg64Blocks, 256, 0, stream>>>(bufB, csr, off, bufC, br2, out, N);
}